// Round 4
// baseline (1857.296 us; speedup 1.0000x reference)
//
#include <hip/hip_runtime.h>
#include <stdint.h>

#define GAS __attribute__((address_space(1)))
#define LAS __attribute__((address_space(3)))

typedef __bf16 v8bf __attribute__((ext_vector_type(8)));
typedef float v4f __attribute__((ext_vector_type(4)));
typedef unsigned short u16;
typedef unsigned long long u64;

constexpr int kB = 256, kT = 128, kI = 512, kH = 1024, kO = 32;
constexpr int kBlocks = 128, kThreads = 512;   // r9: U=32 blocks, 8 waves
constexpr int KSX = kI / 32;   // 16 k-slices of 32 in x
constexpr int KSH = kH / 32;   // 32 k-slices of 32 in h
constexpr int QX = KSX / 4;    // 4  x-slices per kq (k-split)
constexpr int QH = KSH / 4;    // 8  h-slices per kq

// workspace layout (bytes) — EXACT r0 layout (ws ~45 MB: rotation dead, r1/r2)
constexpr size_t OFF_FLG = 0;                                   // flags[4][64], 16B stride
constexpr size_t OFF_H   = 8192;                                // 2 x 512KB frag-layout h
constexpr size_t SZ_H    = (size_t)2 * kB * kH * 2;
constexpr size_t OFF_XT  = OFF_H + SZ_H;                        // frag-tiled x (bf16)
constexpr size_t SZ_XT   = (size_t)kB * kT * kI * 2;            // 32 MB
constexpr size_t OFF_WIT = OFF_XT + SZ_XT;                      // 4 x 1MB wi frag tiles
constexpr size_t SZ_WIT  = (size_t)kH * kI * 2;
constexpr size_t OFF_WHT = OFF_WIT + 4 * SZ_WIT;                // 4 x 2MB wh frag tiles
constexpr size_t SZ_WHT  = (size_t)kH * kH * 2;

struct LstmParams {
  const u16* xt;        // frag-tiled x: [t][mt][mi][ks(16)][lane][8]
  const u16* wit[4];    // frag-tiled wi: [ut16][ks(16)][lane][8], gates i,f,g,o
  const u16* wht[4];    // frag-tiled wh: [ut16][ks(32)][lane][8]
  const float* bi[4];
  const float* bh[4];
  const float* wfc;     // fp32 [O][H]
  float* out;           // fp32 [B][O]
  unsigned* flags;      // [4][64], 16B stride (PRIVATE producer lines)
  u16* hbuf;            // 2 x frag-layout h: [mt][mi][ks(32)][lane][8]
};

static __device__ __forceinline__ float b2f(u16 v) {
  union { float f; uint32_t i; } u; u.i = ((uint32_t)v) << 16; return u.f;
}
static __device__ __forceinline__ u16 f2b(float f) {
  union { float f; uint32_t i; } u; u.f = f;
  return (u16)((u.i + 0x7fffu + ((u.i >> 16) & 1u)) >> 16);
}
static __device__ __forceinline__ float sigm(float x) { return 1.f / (1.f + __expf(-x)); }
static __device__ __forceinline__ float tanh_f(float x) {
  float e = __expf(2.f * x);
  return 1.f - 2.f / (e + 1.f);
}
// coherent async global->LDS, 16B/lane, sc0|sc1 (bypass L1/L2, LLC-serviced).
// r2-r4 PROVEN coherent-read path. RULE (r7): a vmcnt wait MUST sit between
// the issue and any ds_read of the destination (compiler can't see the AS(3)
// dependency). r9: cross-wave sharing of staged data additionally requires a
// block barrier (each wave's own vmcnt(0) runs before it arrives, and
// __syncthreads itself drains vmcnt per-wave).
static __device__ __forceinline__ void ld16c(const void* g, void* l) {
  __builtin_amdgcn_global_load_lds((const GAS uint32_t*)g, (LAS uint32_t*)l, 16, 0, 0x11);
}

// ---- prepass: fp32 -> bf16 frag-tiling (unchanged layouts) ------------------
__global__ __launch_bounds__(256) void cvt_x_tile(const float* __restrict__ x,
                                                  u16* __restrict__ xt) {
  const int gid = blockIdx.x * 256 + threadIdx.x;    // 2^21 threads exactly
  const int lane = gid & 63;
  const int ks = (gid >> 6) & 15;
  const int mi = (gid >> 10) & 3;
  const int mt = (gid >> 12) & 3;
  const int t  = gid >> 14;
  const int m = mt * 64 + mi * 16 + (lane & 15);
  const int k = ks * 32 + (lane >> 4) * 8;
  const float4* s = (const float4*)(x + ((size_t)m * kT + t) * kI + k);
  const float4 a = s[0], b = s[1];
  uint4 o = {f2b(a.x) | ((uint32_t)f2b(a.y) << 16), f2b(a.z) | ((uint32_t)f2b(a.w) << 16),
             f2b(b.x) | ((uint32_t)f2b(b.y) << 16), f2b(b.z) | ((uint32_t)f2b(b.w) << 16)};
  *(uint4*)(xt + (size_t)gid * 8) = o;
}

__global__ __launch_bounds__(256) void cvt_w_tile(const float* __restrict__ w,
                                                  u16* __restrict__ wt,
                                                  int K, int lgKS) {
  const int gid = blockIdx.x * 256 + threadIdx.x;
  const int lane = gid & 63;
  const int rest = gid >> 6;
  const int ks = rest & ((1 << lgKS) - 1);
  const int ut2 = rest >> lgKS;
  const int u = ut2 * 16 + (lane & 15);
  const int k = ks * 32 + (lane >> 4) * 8;
  const float4* s = (const float4*)(w + (size_t)u * K + k);
  const float4 a = s[0], b = s[1];
  uint4 o = {f2b(a.x) | ((uint32_t)f2b(a.y) << 16), f2b(a.z) | ((uint32_t)f2b(a.w) << 16),
             f2b(b.x) | ((uint32_t)f2b(b.y) << 16), f2b(b.z) | ((uint32_t)f2b(b.w) << 16)};
  *(uint4*)(wt + (size_t)gid * 8) = o;
}

// ---- persistent recurrence kernel ------------------------------------------
// r9 structure: 128 blocks x 512 threads. Block = (mt, us) with us=blk>>2
// owning 32 units (= h-slice us of the next step, published as 4 x 1KB runs).
// Wave w: kq = w>>1 (K-quarter), uh = w&1 (unit half); utl = us*2+uh is the
// old 16-unit column id. The 128 KB group h-tile is staged ONCE per block
// (4 x 32KB kq regions, 2 waves share each) -> coherent LLC read traffic
// halves: 32 -> 16 MB/step.
__global__ __launch_bounds__(kThreads, 2) void lstm_kernel(LstmParams p) {
  // LDS map: [0,128K) kq staging regions (32 KB each); Red (128 KB) overlaid
  // on [0,128K) — protected by the barrier after phase-H consume.
  // [128K,132K) Hout repack tile (64 rows x 32 units). shFC (16 KB) overlaid
  // at 0 post-loop.
  __shared__ __align__(16) char smem[135168];
  v4f* Red = (v4f*)smem;              // [slot = (uh*4+kq)*16 + g*4 + m][lane]
  u16* Hout = (u16*)(smem + 131072);  // [64 rows][32 units]
  u16* shFC = (u16*)smem;             // 8 rows x 1024 bf16 (post-loop only)

  const int tid = threadIdx.x;
  const int lane = tid & 63;
  const int wv = tid >> 6;           // 0..7
  const int kq = wv >> 1;            // K-quarter owner AND row-16-group owner in combine
  const int uh = wv & 1;             // unit half (16 of the block's 32 units)
  const int blk = blockIdx.x;
  const int mt = blk & 3;            // batch tile 0..3 = barrier group
  const int us = blk >> 2;           // 0..31: h-slice / 32-unit column
  const int utl = us * 2 + uh;       // old 16-unit column id 0..63

  const int mloc = lane & 15;
  const int q = lane >> 4;
  const int uglob = us * 32 + uh * 16 + mloc;

  unsigned* gflags = p.flags + mt * 256;   // 32 used slots, stride 4 u32 (16B)

  float bias[4];
#pragma unroll
  for (int g = 0; g < 4; ++g) bias[g] = p.bi[g][uglob] + p.bh[g][uglob];

  float creg[4] = {0.f, 0.f, 0.f, 0.f};    // cell state rows mt*64+kq*16+q*4+r

  // ---- h-weights resident in registers (128 VGPRs); x-weights streamed ----
  v8bf bhh[QH][4];
#pragma unroll
  for (int g = 0; g < 4; ++g)
#pragma unroll
    for (int i = 0; i < QH; ++i)
      bhh[i][g] = *((const v8bf*)p.wht[g] + ((size_t)(utl * KSH + kq * QH + i) * 64 + lane));

  for (int t = 0; t < kT; ++t) {
    v4f acc[4][4];    // [row-16-group mi][gate] partials for this wave's K-quarter
#pragma unroll
    for (int m = 0; m < 4; ++m)
#pragma unroll
      for (int g = 0; g < 4; ++g) acc[m][g] = (v4f){0.f, 0.f, 0.f, 0.f};

    // ---- phase X: x-part MFMAs, pre-poll (independent of h); wi from L2 ----
    const v8bf* xf = (const v8bf*)p.xt + ((size_t)(t * 4 + mt) * 4 * KSX) * 64;
#pragma unroll
    for (int i = 0; i < QX; ++i) {
      v8bf bxl[4];
#pragma unroll
      for (int g = 0; g < 4; ++g)
        bxl[g] = *((const v8bf*)p.wit[g] + ((size_t)(utl * KSX + kq * QX + i) * 64 + lane));
#pragma unroll
      for (int mi = 0; mi < 4; ++mi) {
        const v8bf a = xf[(size_t)(mi * KSX + kq * QX + i) * 64 + lane];
#pragma unroll
        for (int g = 0; g < 4; ++g)
          acc[mi][g] = __builtin_amdgcn_mfma_f32_16x16x32_bf16(a, bxl[g], acc[mi][g], 0, 0, 0);
      }
    }

    if (t > 0) {
      if (wv == 0) {   // group barrier: poll 32 PRIVATE padded producer flags
        while (true) {
          unsigned v = __hip_atomic_load(&gflags[(lane & 31) * 4], __ATOMIC_RELAXED,
                                         __HIP_MEMORY_SCOPE_AGENT);
          if (__ballot(v >= (unsigned)t) == ~0ull) break;
          __builtin_amdgcn_s_sleep(1);
        }
      }
      __syncthreads();   // release all waves past the barrier

      // ---- phase H: the 2 waves of kq co-stage the 32 KB kq region (16 x
      // 1KB ld16c each), compute OWN staged mi-pair on per-wave counted
      // vmcnt (r3-proven overlap), barrier, then compute partner's pair.
      const char* hread = (const char*)(p.hbuf + (size_t)(t & 1) * kB * kH);
      char* kqs = smem + kq * 32768;   // [mi][i] x 1KB

#define STAGE_MI(MI)                                                          \
  _Pragma("unroll")                                                           \
  for (int i = 0; i < QH; ++i) {                                              \
    const size_t sl = (size_t)((mt * 4 + (MI)) * KSH + kq * QH + i);          \
    ld16c(hread + sl * 1024 + lane * 16, kqs + ((MI) * QH + i) * 1024);       \
  }
#define COMPUTE_MI(MI)                                                        \
  _Pragma("unroll")                                                           \
  for (int i = 0; i < QH; ++i) {                                              \
    const v8bf a = *(const v8bf*)(kqs + ((MI) * QH + i) * 1024 + lane * 16);  \
    _Pragma("unroll")                                                         \
    for (int g = 0; g < 4; ++g)                                               \
      acc[(MI)][g] =                                                          \
          __builtin_amdgcn_mfma_f32_16x16x32_bf16(a, bhh[i][g], acc[(MI)][g], \
                                                  0, 0, 0);                   \
  }

      if (uh == 0) {   // wave-uniform branch; barriers stay at uniform points
        STAGE_MI(0) STAGE_MI(1)
        asm volatile("s_waitcnt vmcnt(8)" ::: "memory");
        __builtin_amdgcn_sched_barrier(0);
        COMPUTE_MI(0)
        asm volatile("s_waitcnt vmcnt(0)" ::: "memory");
        __builtin_amdgcn_sched_barrier(0);
        COMPUTE_MI(1)
      } else {
        STAGE_MI(2) STAGE_MI(3)
        asm volatile("s_waitcnt vmcnt(8)" ::: "memory");
        __builtin_amdgcn_sched_barrier(0);
        COMPUTE_MI(2)
        asm volatile("s_waitcnt vmcnt(0)" ::: "memory");
        __builtin_amdgcn_sched_barrier(0);
        COMPUTE_MI(3)
      }
      __syncthreads();   // partner's staging complete (its vmcnt drained)
      if (uh == 0) {
        COMPUTE_MI(2) COMPUTE_MI(3)
      } else {
        COMPUTE_MI(0) COMPUTE_MI(1)
      }
#undef STAGE_MI
#undef COMPUTE_MI
    }

    __syncthreads();   // all phase-H ds_reads done: Red overlay now safe

    // ---- cross-wave K-reduction through LDS (per unit-half) ----
#pragma unroll
    for (int m = 0; m < 4; ++m)
#pragma unroll
      for (int g = 0; g < 4; ++g)
        Red[((uh * 4 + kq) * 16 + g * 4 + m) * 64 + lane] = acc[m][g];
    __syncthreads();

    // combine: this thread owns rows mt*64+kq*16+q*4+{0..3}, unit uglob
    v4f gacc[4];
#pragma unroll
    for (int g = 0; g < 4; ++g) {
      v4f s = Red[((uh * 4 + 0) * 16 + g * 4 + kq) * 64 + lane];
#pragma unroll
      for (int kqp = 1; kqp < 4; ++kqp) {
        const v4f z = Red[((uh * 4 + kqp) * 16 + g * 4 + kq) * 64 + lane];
#pragma unroll
        for (int r = 0; r < 4; ++r) s[r] += z[r];
      }
      gacc[g] = s;
    }

    // gates -> h; repack through Hout so global stores are coalesced 8B
#pragma unroll
    for (int r = 0; r < 4; ++r) {
      const float iv = sigm(gacc[0][r] + bias[0]);
      const float fv = sigm(gacc[1][r] + bias[1]);
      const float gv = tanh_f(gacc[2][r] + bias[2]);
      const float ov = sigm(gacc[3][r] + bias[3]);
      creg[r] = fv * creg[r] + iv * gv;
      const float hv = ov * tanh_f(creg[r]);
      Hout[(kq * 16 + q * 4 + r) * 32 + uh * 16 + mloc] = f2b(hv);
    }
    __syncthreads();   // Hout complete

    // coalesced write-through: this block's h IS slice ks=us of each mi ->
    // 4 contiguous 1KB runs. 512 threads x 8B. Slice frag: [L=row16|kg<<4]
    // [8 units x 2B], unit-in-block = kg*8 + j.
    {
      u16* hw = p.hbuf + (size_t)((t + 1) & 1) * kB * kH;
      const int mi_s = tid >> 7;        // 0..3
      const int idx = tid & 127;
      const int L = idx >> 1;           // 0..63
      const int j0 = (idx & 1) * 4;
      const int row16 = L & 15;
      const int kg = L >> 4;
      const u64 v = *(const u64*)&Hout[(mi_s * 16 + row16) * 32 + kg * 8 + j0];
      u64* dst = (u64*)((char*)hw + ((size_t)((mt * 4 + mi_s) * KSH + us) * 1024)
                        + kg * 256 + row16 * 16 + j0 * 2);
      __hip_atomic_store(dst, v, __ATOMIC_RELAXED, __HIP_MEMORY_SCOPE_AGENT);
    }

    __syncthreads();   // drains vmcnt: all h stores acked at LLC (r4-validated)
    if (tid == 0)
      __hip_atomic_fetch_add(&gflags[us * 4], 1u, __ATOMIC_RELAXED,
                             __HIP_MEMORY_SCOPE_AGENT);
  }

  // ---- FC + log_softmax: blocks 0..31, 8 rows x 32 cols. h_last in buf 0 ----
  if (blk < 32) {
    const int gg = blk >> 3;   // mt of rows blk*8..+8
    if (wv == 0) {
      while (true) {
        unsigned v = __hip_atomic_load(&p.flags[gg * 256 + (lane & 31) * 4],
                                       __ATOMIC_RELAXED, __HIP_MEMORY_SCOPE_AGENT);
        if (__ballot(v >= (unsigned)kT) == ~0ull) break;
        __builtin_amdgcn_s_sleep(1);
      }
    }
    __syncthreads();
    // stage 8 rows from frag-layout h into shFC[row][u] (first 256 threads)
    if (tid < 256) {
      const int mi = (blk >> 1) & 3;
      const int ks2 = tid >> 3;        // 0..31
      const int ug = (tid >> 1) & 3;   // unit 8-group
      const int rh = tid & 1;          // row half
      u64* hf = (u64*)p.hbuf;          // buffer 0 (kT even)
#pragma unroll
      for (int rr = 0; rr < 4; ++rr) {
        const int row_l = rh * 4 + rr;
        const int r16 = (blk & 1) * 8 + row_l;
        const int L = r16 | (ug << 4);
        const size_t fi = ((size_t)((gg * 4 + mi) * KSH + ks2) * 64 + L) * 2;
        const u64 a = __hip_atomic_load(hf + fi, __ATOMIC_RELAXED, __HIP_MEMORY_SCOPE_AGENT);
        const u64 b = __hip_atomic_load(hf + fi + 1, __ATOMIC_RELAXED, __HIP_MEMORY_SCOPE_AGENT);
        u64* d = (u64*)&shFC[row_l * kH + ks2 * 32 + ug * 8];
        d[0] = a; d[1] = b;
      }
    }
    __syncthreads();
    if (tid < 256) {
      const int row = tid >> 5;
      const int col = tid & 31;
      const u16* hr = &shFC[row * kH];
      const float* wr = p.wfc + (size_t)col * kH;
      float s = 0.f;
      for (int k = 0; k < kH; k += 4) {
        const float4 w4 = *(const float4*)(wr + k);
        s += b2f(hr[k]) * w4.x + b2f(hr[k + 1]) * w4.y +
             b2f(hr[k + 2]) * w4.z + b2f(hr[k + 3]) * w4.w;
      }
      float mx = s;
#pragma unroll
      for (int off = 16; off; off >>= 1) mx = fmaxf(mx, __shfl_xor(mx, off, 32));
      const float ex = __expf(s - mx);
      float se = ex;
#pragma unroll
      for (int off = 16; off; off >>= 1) se += __shfl_xor(se, off, 32);
      p.out[(blk * 8 + row) * kO + col] = s - mx - __logf(se);
    }
  }
}

extern "C" void kernel_launch(void* const* d_in, const int* in_sizes, int n_in,
                              void* d_out, int out_size, void* d_ws, size_t ws_size,
                              hipStream_t stream) {
  (void)in_sizes; (void)n_in; (void)out_size; (void)ws_size;
  char* ws = (char*)d_ws;

  u16* xt = (u16*)(ws + OFF_XT);
  u16 *wit[4], *wht[4];
  for (int g = 0; g < 4; ++g) {
    wit[g] = (u16*)(ws + OFF_WIT + (size_t)g * SZ_WIT);
    wht[g] = (u16*)(ws + OFF_WHT + (size_t)g * SZ_WHT);
  }

  // dict order: x, (w_ii,w_hi,b_ii,b_hi), (w_if,w_hf,b_if,b_hf),
  //             (w_io,w_ho,b_io,b_ho), (w_ic,w_hc,b_ic,b_hc), w_fc
  // gate order: 0=i, 1=f, 2=g(candidate), 3=o
  const int gsrc[4] = {1, 5, 13, 9};

  hipMemsetAsync(d_ws, 0, 8192, stream);   // zero barrier flags

  cvt_x_tile<<<8192, 256, 0, stream>>>((const float*)d_in[0], xt);
  for (int g = 0; g < 4; ++g) {
    cvt_w_tile<<<256, 256, 0, stream>>>((const float*)d_in[gsrc[g]], wit[g], kI, 4);
    cvt_w_tile<<<512, 256, 0, stream>>>((const float*)d_in[gsrc[g] + 1], wht[g], kH, 5);
  }

  LstmParams p;
  p.xt = xt;
  for (int g = 0; g < 4; ++g) {
    p.wit[g] = wit[g];
    p.wht[g] = wht[g];
    p.bi[g] = (const float*)d_in[gsrc[g] + 2];
    p.bh[g] = (const float*)d_in[gsrc[g] + 3];
  }
  p.wfc = (const float*)d_in[17];
  p.out = (float*)d_out;
  p.flags = (unsigned*)(ws + OFF_FLG);
  p.hbuf = (u16*)(ws + OFF_H);

  void* args[] = {&p};
  hipError_t e = hipLaunchCooperativeKernel((void*)lstm_kernel, dim3(kBlocks),
                                            dim3(kThreads), args, 0, stream);
  if (e != hipSuccess) {
    // Never fail silently (r5 lesson). 128 blocks x 512 thr at 135KB LDS =
    // 1 block/CU -> all blocks co-resident on 256 CUs even without coop.
    (void)hipGetLastError();   // clear sticky error
    lstm_kernel<<<dim3(kBlocks), dim3(kThreads), 0, stream>>>(p);
  }
}

// Round 5
// 1216.197 us; speedup vs baseline: 1.5271x; 1.5271x over previous
//
#include <hip/hip_runtime.h>
#include <stdint.h>

#define GAS __attribute__((address_space(1)))
#define LAS __attribute__((address_space(3)))

typedef __bf16 v8bf __attribute__((ext_vector_type(8)));
typedef float v4f __attribute__((ext_vector_type(4)));
typedef unsigned short u16;
typedef unsigned long long u64;

constexpr int kB = 256, kT = 128, kI = 512, kH = 1024, kO = 32;
constexpr int kBlocks = 512, kThreads = 256;   // r5: 2 blocks/CU (32-row groups)
constexpr int KSX = kI / 32;   // 16 k-slices of 32 in x
constexpr int KSH = kH / 32;   // 32 k-slices of 32 in h
constexpr int QX = KSX / 4;    // 4  x-slices per wave (k-split)
constexpr int QH = KSH / 4;    // 8  h-slices per wave

// workspace layout (bytes) — EXACT r0 layout (ws ~45 MB: rotation dead, r1/r2)
constexpr size_t OFF_FLG = 0;                                   // flags[8][64], 16B stride = 8 KB
constexpr size_t OFF_H   = 8192;                                // 2 x 512KB frag-layout h
constexpr size_t SZ_H    = (size_t)2 * kB * kH * 2;
constexpr size_t OFF_XT  = OFF_H + SZ_H;                        // frag-tiled x (bf16)
constexpr size_t SZ_XT   = (size_t)kB * kT * kI * 2;            // 32 MB
constexpr size_t OFF_WIT = OFF_XT + SZ_XT;                      // 4 x 1MB wi frag tiles
constexpr size_t SZ_WIT  = (size_t)kH * kI * 2;
constexpr size_t OFF_WHT = OFF_WIT + 4 * SZ_WIT;                // 4 x 2MB wh frag tiles
constexpr size_t SZ_WHT  = (size_t)kH * kH * 2;

struct LstmParams {
  const u16* xt;        // frag-tiled x: [t][mt4][mi][ks(16)][lane][8]
  const u16* wit[4];    // frag-tiled wi: [ut][ks(16)][lane][8], gates i,f,g,o
  const u16* wht[4];    // frag-tiled wh: [ut][ks(32)][lane][8]
  const float* bi[4];
  const float* bh[4];
  const float* wfc;     // fp32 [O][H]
  float* out;           // fp32 [B][O]
  unsigned* flags;      // [8 groups][64 producers], 16B stride (PRIVATE lines)
  u16* hbuf;            // 2 x frag-layout h: [mt4][mi][ks(32)][lane][8]
};

static __device__ __forceinline__ float b2f(u16 v) {
  union { float f; uint32_t i; } u; u.i = ((uint32_t)v) << 16; return u.f;
}
static __device__ __forceinline__ u16 f2b(float f) {
  union { float f; uint32_t i; } u; u.f = f;
  return (u16)((u.i + 0x7fffu + ((u.i >> 16) & 1u)) >> 16);
}
static __device__ __forceinline__ float sigm(float x) { return 1.f / (1.f + __expf(-x)); }
static __device__ __forceinline__ float tanh_f(float x) {
  float e = __expf(2.f * x);
  return 1.f - 2.f / (e + 1.f);
}
// coherent async global->LDS, 16B/lane, sc0|sc1 (bypass L1/L2, LLC-serviced).
// r2-r4 PROVEN coherent-read path. RULE (r7): a vmcnt wait MUST sit between
// the issue and any ds_read of the destination (compiler can't see the AS(3)
// dependency). RULE (r9/r4 post-mortem): phase H must stay PER-WAVE private —
// a cross-wave barrier inside phase H (partner-staged data) costs ~3 us/step.
static __device__ __forceinline__ void ld16c(const void* g, void* l) {
  __builtin_amdgcn_global_load_lds((const GAS uint32_t*)g, (LAS uint32_t*)l, 16, 0, 0x11);
}

// ---- prepass: fp32 -> bf16 frag-tiling (unchanged layouts) ------------------
__global__ __launch_bounds__(256) void cvt_x_tile(const float* __restrict__ x,
                                                  u16* __restrict__ xt) {
  const int gid = blockIdx.x * 256 + threadIdx.x;    // 2^21 threads exactly
  const int lane = gid & 63;
  const int ks = (gid >> 6) & 15;
  const int mi = (gid >> 10) & 3;
  const int mt = (gid >> 12) & 3;
  const int t  = gid >> 14;
  const int m = mt * 64 + mi * 16 + (lane & 15);
  const int k = ks * 32 + (lane >> 4) * 8;
  const float4* s = (const float4*)(x + ((size_t)m * kT + t) * kI + k);
  const float4 a = s[0], b = s[1];
  uint4 o = {f2b(a.x) | ((uint32_t)f2b(a.y) << 16), f2b(a.z) | ((uint32_t)f2b(a.w) << 16),
             f2b(b.x) | ((uint32_t)f2b(b.y) << 16), f2b(b.z) | ((uint32_t)f2b(b.w) << 16)};
  *(uint4*)(xt + (size_t)gid * 8) = o;
}

__global__ __launch_bounds__(256) void cvt_w_tile(const float* __restrict__ w,
                                                  u16* __restrict__ wt,
                                                  int K, int lgKS) {
  const int gid = blockIdx.x * 256 + threadIdx.x;
  const int lane = gid & 63;
  const int rest = gid >> 6;
  const int ks = rest & ((1 << lgKS) - 1);
  const int ut2 = rest >> lgKS;
  const int u = ut2 * 16 + (lane & 15);
  const int k = ks * 32 + (lane >> 4) * 8;
  const float4* s = (const float4*)(w + (size_t)u * K + k);
  const float4 a = s[0], b = s[1];
  uint4 o = {f2b(a.x) | ((uint32_t)f2b(a.y) << 16), f2b(a.z) | ((uint32_t)f2b(a.w) << 16),
             f2b(b.x) | ((uint32_t)f2b(b.y) << 16), f2b(b.z) | ((uint32_t)f2b(b.w) << 16)};
  *(uint4*)(wt + (size_t)gid * 8) = o;
}

// ---- persistent recurrence kernel ------------------------------------------
// r5 structure: 512 blocks x 256 threads, 2 blocks/CU. Block = (mt8, ut):
// mt8 = blk>>6 (8 groups of 32 batch rows, GROUP-CONTIGUOUS for fallback
// safety), ut = blk&63 (16 hidden units x 4 gates — identical to r3's ut).
// Wave wv = K-quarter owner (r3 semantics). Per block: 2 mi sub-tiles
// (mib = (mt8&1)*2), staging 64 KB, Red 32 KB overlay -> LDS 66.5 KB ->
// TWO co-resident blocks per CU interleave their latency phases.
__global__ __launch_bounds__(kThreads, 2) void lstm_kernel(LstmParams p) {
  // LDS map: [0,64K) per-wave 16 KB staging; Red (32 KB) overlaid on [0,32K)
  // — protected by the barrier after phase-H consume. [64K,65K) Hout
  // [32 rows][16 units]. shFC (16 KB) overlaid at 0 post-loop.
  __shared__ __align__(16) char smem[66560];
  v4f* Red = (v4f*)smem;              // [slot = kq*8 + ml*4 + g][lane]
  float* Redf = (float*)smem;
  u16* Hout = (u16*)(smem + 65536);   // [32 rows][16 units]
  u16* shFC = (u16*)smem;             // 8 rows x 1024 bf16 (post-loop only)

  const int tid = threadIdx.x;
  const int lane = tid & 63;
  const int wv = tid >> 6;           // K-quarter owner
  const int blk = blockIdx.x;
  const int mt8 = blk >> 6;          // group 0..7 = 32 batch rows
  const int ut = blk & 63;           // unit column (16 units x 4 gates)
  const int mt4 = mt8 >> 1;          // frag-layout batch tile
  const int mib = (mt8 & 1) * 2;     // mi base within mt4 (2 sub-tiles)

  const int mloc = lane & 15;
  const int q = lane >> 4;
  const int uglob = ut * 16 + mloc;

  unsigned* gflags = p.flags + mt8 * 256;   // 64 slots, stride 4 u32 (16B)

  float bias[4];
#pragma unroll
  for (int g = 0; g < 4; ++g) bias[g] = p.bi[g][uglob] + p.bh[g][uglob];

  float creg[2] = {0.f, 0.f};   // cell state for rows mt8*32 + wv*8 + q*2 + r

  // ---- h-weights resident in registers (128 VGPRs); x-weights streamed ----
  v8bf bhh[QH][4];
#pragma unroll
  for (int g = 0; g < 4; ++g)
#pragma unroll
    for (int i = 0; i < QH; ++i)
      bhh[i][g] = *((const v8bf*)p.wht[g] + ((size_t)(ut * KSH + wv * QH + i) * 64 + lane));

  for (int t = 0; t < kT; ++t) {
    v4f acc[2][4];    // [mi_loc][gate] partials for this wave's K-quarter
#pragma unroll
    for (int m = 0; m < 2; ++m)
#pragma unroll
      for (int g = 0; g < 4; ++g) acc[m][g] = (v4f){0.f, 0.f, 0.f, 0.f};

    // ---- phase X: x-part MFMAs, pre-poll (independent of h); wi from L2 ----
    const v8bf* xf = (const v8bf*)p.xt + ((size_t)(t * 4 + mt4) * 4 * KSX) * 64;
#pragma unroll
    for (int i = 0; i < QX; ++i) {
      v8bf bxl[4];
#pragma unroll
      for (int g = 0; g < 4; ++g)
        bxl[g] = *((const v8bf*)p.wit[g] + ((size_t)(ut * KSX + wv * QX + i) * 64 + lane));
#pragma unroll
      for (int ml = 0; ml < 2; ++ml) {
        const v8bf a = xf[(size_t)((mib + ml) * KSX + wv * QX + i) * 64 + lane];
#pragma unroll
        for (int g = 0; g < 4; ++g)
          acc[ml][g] = __builtin_amdgcn_mfma_f32_16x16x32_bf16(a, bxl[g], acc[ml][g], 0, 0, 0);
      }
    }

    if (t > 0) {
      if (wv == 0) {   // group barrier: 64 lanes poll 64 PRIVATE padded flags
        while (true) {
          unsigned v = __hip_atomic_load(&gflags[lane * 4], __ATOMIC_RELAXED,
                                         __HIP_MEMORY_SCOPE_AGENT);
          if (__ballot(v >= (unsigned)t) == ~0ull) break;
          __builtin_amdgcn_s_sleep(1);
        }
      }
      __syncthreads();   // release all waves; also drains each wave's vmcnt
                         // so the counted waits below see exactly our issues

      // ---- phase H: per-wave private (r4 lesson). Stage this wave's 16 KB
      // (2 mi x 8 slices) via coherent global_load_lds; counted-vmcnt overlap
      // (r3-proven): compute mi0 while mi1 streams.
      const char* hread = (const char*)(p.hbuf + (size_t)(t & 1) * kB * kH);
      char* myHs = smem + wv * 16384;

#define STAGE_ML(ML)                                                          \
  _Pragma("unroll")                                                           \
  for (int i = 0; i < QH; ++i) {                                              \
    const size_t sl = (size_t)((mt4 * 4 + mib + (ML)) * KSH + wv * QH + i);   \
    ld16c(hread + sl * 1024 + lane * 16, myHs + ((ML) * QH + i) * 1024);      \
  }
#define COMPUTE_ML(ML)                                                        \
  _Pragma("unroll")                                                           \
  for (int i = 0; i < QH; ++i) {                                              \
    const v8bf a = *(const v8bf*)(myHs + ((ML) * QH + i) * 1024 + lane * 16); \
    _Pragma("unroll")                                                         \
    for (int g = 0; g < 4; ++g)                                               \
      acc[(ML)][g] = __builtin_amdgcn_mfma_f32_16x16x32_bf16(                 \
          a, bhh[i][g], acc[(ML)][g], 0, 0, 0);                               \
  }

      STAGE_ML(0) STAGE_ML(1)
      asm volatile("s_waitcnt vmcnt(8)" ::: "memory");
      __builtin_amdgcn_sched_barrier(0);
      COMPUTE_ML(0)
      asm volatile("s_waitcnt vmcnt(0)" ::: "memory");
      __builtin_amdgcn_sched_barrier(0);
      COMPUTE_ML(1)
#undef STAGE_ML
#undef COMPUTE_ML
    }

    __syncthreads();   // all phase-H ds_reads done: Red overlay now safe

    // ---- cross-wave K-reduction through LDS ----
#pragma unroll
    for (int ml = 0; ml < 2; ++ml)
#pragma unroll
      for (int g = 0; g < 4; ++g)
        Red[(wv * 8 + ml * 4 + g) * 64 + lane] = acc[ml][g];
    __syncthreads();

    // combine + gates: this thread owns rows mt8*32 + wv*8 + q*2 + {0,1},
    // unit uglob. C-frag element: row16 = q'*4 + reg, col = lane&15.
#pragma unroll
    for (int r = 0; r < 2; ++r) {
      const int lrow = wv * 8 + q * 2 + r;
      const int ml = lrow >> 4;
      const int r16 = lrow & 15;
      const int qp = r16 >> 2;
      const int reg = r16 & 3;
      float gacc[4];
#pragma unroll
      for (int g = 0; g < 4; ++g) {
        float s = 0.f;
#pragma unroll
        for (int kq = 0; kq < 4; ++kq)
          s += Redf[((kq * 8 + ml * 4 + g) * 64 + qp * 16 + mloc) * 4 + reg];
        gacc[g] = s;
      }
      const float iv = sigm(gacc[0] + bias[0]);
      const float fv = sigm(gacc[1] + bias[1]);
      const float gv = tanh_f(gacc[2] + bias[2]);
      const float ov = sigm(gacc[3] + bias[3]);
      creg[r] = fv * creg[r] + iv * gv;
      const float hv = ov * tanh_f(creg[r]);
      Hout[lrow * 16 + mloc] = f2b(hv);
    }
    __syncthreads();   // Hout complete

    // coalesced write-through: this block's h = 4 contiguous 256B runs
    // (mi_loc 0..1) x (hbit 0..1); 128 threads x 8B.
    if (tid < 128) {
      u16* hw = p.hbuf + (size_t)((t + 1) & 1) * kB * kH;
      const int run = tid >> 5;        // 0..3
      const int ml = run >> 1;
      const int hbit = run & 1;
      const int idx = tid & 31;
      const int row16 = idx >> 1;
      const int j0 = (idx & 1) * 4;
      const int hi = (ut & 1) * 2 + hbit;
      const u64 v = *(const u64*)&Hout[(ml * 16 + row16) * 16 + hbit * 8 + j0];
      u64* dst = (u64*)((char*)hw +
                        ((size_t)((mt4 * 4 + mib + ml) * KSH + (ut >> 1)) * 1024) +
                        hi * 256 + row16 * 16 + j0 * 2);
      __hip_atomic_store(dst, v, __ATOMIC_RELAXED, __HIP_MEMORY_SCOPE_AGENT);
    }

    __syncthreads();   // drains vmcnt: all h stores acked at LLC (r4-validated)
    if (tid == 0)
      __hip_atomic_fetch_add(&gflags[ut * 4], 1u, __ATOMIC_RELAXED,
                             __HIP_MEMORY_SCOPE_AGENT);
  }

  // ---- FC + log_softmax: blocks 0..31, 8 rows x 32 cols. h_last in buf 0 ----
  if (blk < 32) {
    const int gg8 = blk >> 2;   // mt8 group of rows blk*8..+8
    if (wv == 0) {
      while (true) {
        unsigned v = __hip_atomic_load(&p.flags[gg8 * 256 + lane * 4], __ATOMIC_RELAXED,
                                       __HIP_MEMORY_SCOPE_AGENT);
        if (__ballot(v >= (unsigned)kT) == ~0ull) break;
        __builtin_amdgcn_s_sleep(1);
      }
    }
    __syncthreads();
    // stage 8 rows from frag-layout h into shFC[row][u] (small, once)
    {
      const int gg4 = blk >> 3;        // mt4 for frag indexing
      const int mi = (blk >> 1) & 3;
      const int ks2 = tid >> 3;        // 0..31
      const int ug = (tid >> 1) & 3;   // unit 8-group
      const int rh = tid & 1;          // row half
      u64* hf = (u64*)p.hbuf;          // buffer 0 (kT even)
#pragma unroll
      for (int rr = 0; rr < 4; ++rr) {
        const int row_l = rh * 4 + rr;
        const int r16 = (blk & 1) * 8 + row_l;
        const int L = r16 | (ug << 4);
        const size_t fi = ((size_t)((gg4 * 4 + mi) * KSH + ks2) * 64 + L) * 2;
        const u64 a = __hip_atomic_load(hf + fi, __ATOMIC_RELAXED, __HIP_MEMORY_SCOPE_AGENT);
        const u64 b = __hip_atomic_load(hf + fi + 1, __ATOMIC_RELAXED, __HIP_MEMORY_SCOPE_AGENT);
        u64* d = (u64*)&shFC[row_l * kH + ks2 * 32 + ug * 8];
        d[0] = a; d[1] = b;
      }
    }
    __syncthreads();
    const int row = tid >> 5;
    const int col = tid & 31;
    const u16* hr = &shFC[row * kH];
    const float* wr = p.wfc + (size_t)col * kH;
    float s = 0.f;
    for (int k = 0; k < kH; k += 4) {
      const float4 w4 = *(const float4*)(wr + k);
      s += b2f(hr[k]) * w4.x + b2f(hr[k + 1]) * w4.y +
           b2f(hr[k + 2]) * w4.z + b2f(hr[k + 3]) * w4.w;
    }
    float mx = s;
#pragma unroll
    for (int off = 16; off; off >>= 1) mx = fmaxf(mx, __shfl_xor(mx, off, 32));
    const float ex = __expf(s - mx);
    float se = ex;
#pragma unroll
    for (int off = 16; off; off >>= 1) se += __shfl_xor(se, off, 32);
    p.out[(blk * 8 + row) * kO + col] = s - mx - __logf(se);
  }
}

extern "C" void kernel_launch(void* const* d_in, const int* in_sizes, int n_in,
                              void* d_out, int out_size, void* d_ws, size_t ws_size,
                              hipStream_t stream) {
  (void)in_sizes; (void)n_in; (void)out_size; (void)ws_size;
  char* ws = (char*)d_ws;

  u16* xt = (u16*)(ws + OFF_XT);
  u16 *wit[4], *wht[4];
  for (int g = 0; g < 4; ++g) {
    wit[g] = (u16*)(ws + OFF_WIT + (size_t)g * SZ_WIT);
    wht[g] = (u16*)(ws + OFF_WHT + (size_t)g * SZ_WHT);
  }

  // dict order: x, (w_ii,w_hi,b_ii,b_hi), (w_if,w_hf,b_if,b_hf),
  //             (w_io,w_ho,b_io,b_ho), (w_ic,w_hc,b_ic,b_hc), w_fc
  // gate order: 0=i, 1=f, 2=g(candidate), 3=o
  const int gsrc[4] = {1, 5, 13, 9};

  hipMemsetAsync(d_ws, 0, 8192, stream);   // zero barrier flags (8 groups x 64)

  cvt_x_tile<<<8192, 256, 0, stream>>>((const float*)d_in[0], xt);
  for (int g = 0; g < 4; ++g) {
    cvt_w_tile<<<256, 256, 0, stream>>>((const float*)d_in[gsrc[g]], wit[g], kI, 4);
    cvt_w_tile<<<512, 256, 0, stream>>>((const float*)d_in[gsrc[g] + 1], wht[g], kH, 5);
  }

  LstmParams p;
  p.xt = xt;
  for (int g = 0; g < 4; ++g) {
    p.wit[g] = wit[g];
    p.wht[g] = wht[g];
    p.bi[g] = (const float*)d_in[gsrc[g] + 2];
    p.bh[g] = (const float*)d_in[gsrc[g] + 3];
  }
  p.wfc = (const float*)d_in[17];
  p.out = (float*)d_out;
  p.flags = (unsigned*)(ws + OFF_FLG);
  p.hbuf = (u16*)(ws + OFF_H);

  void* args[] = {&p};
  hipError_t e = hipLaunchCooperativeKernel((void*)lstm_kernel, dim3(kBlocks),
                                            dim3(kThreads), args, 0, stream);
  if (e != hipSuccess) {
    // Never fail silently (r5 lesson). __launch_bounds__(256,2) + 66.5 KB LDS
    // guarantee 2 blocks/CU -> all 512 blocks co-resident on 256 CUs; the
    // group-contiguous mapping additionally makes partial residency safe.
    (void)hipGetLastError();   // clear sticky error
    lstm_kernel<<<dim3(kBlocks), dim3(kThreads), 0, stream>>>(p);
  }
}